// Round 1
// baseline (1367.926 us; speedup 1.0000x reference)
//
#include <hip/hip_runtime.h>
#include <math.h>

#define N_NODES 20000
#define N_DIM   128
#define N_EDGES 640000
#define LN_EPS  1e-5f

// ---- order-preserving float <-> uint32 encoding for atomicMax ----
__device__ __forceinline__ unsigned enc_f(float f) {
    unsigned b = __float_as_uint(f);
    return (b & 0x80000000u) ? ~b : (b | 0x80000000u);
}
__device__ __forceinline__ float dec_f(unsigned u) {
    unsigned b = (u & 0x80000000u) ? (u ^ 0x80000000u) : ~u;
    return __uint_as_float(b);
}
#define ENC_NEG_INF 0x007FFFFFu   // enc(-inf): no finite msg encodes <= this

__device__ __forceinline__ float gelu_exact(float v) {
    return 0.5f * v * (1.0f + erff(v * 0.70710678118654752f));
}

// ---------------- kernel 1: init agg workspace to enc(-inf) ----------------
__global__ void init_agg_kernel(unsigned* __restrict__ agg) {
    int i = blockIdx.x * blockDim.x + threadIdx.x;   // N*D/4 threads exactly
    uint4 v = make_uint4(ENC_NEG_INF, ENC_NEG_INF, ENC_NEG_INF, ENC_NEG_INF);
    ((uint4*)agg)[i] = v;
}

// ---------------- kernel 2: edge scatter-max ----------------
// 32 threads per edge; each thread handles 4 contiguous dims (float4).
__global__ void scatter_max_kernel(const float* __restrict__ x,
                                   const int* __restrict__ ei,
                                   const float* __restrict__ ew,
                                   unsigned* __restrict__ agg) {
    int t = blockIdx.x * blockDim.x + threadIdx.x;
    int e = t >> 5;
    if (e >= N_EDGES) return;
    int q = (t & 31) << 2;
    int src = ei[e];
    int dst = ei[N_EDGES + e];
    float w = ew[e];
    float4 xv = *(const float4*)(x + (size_t)src * N_DIM + q);
    unsigned* a = agg + (size_t)dst * N_DIM + q;
    atomicMax(a + 0, enc_f(xv.x * w));
    atomicMax(a + 1, enc_f(xv.y * w));
    atomicMax(a + 2, enc_f(xv.z * w));
    atomicMax(a + 3, enc_f(xv.w * w));
}

// ---------------- kernel 3: fused per-node pipeline ----------------
// 1 wave per node, 4 nodes per 256-thread block. Each lane owns dims
// d0=lane, d1=lane+64. Row data staged in LDS (broadcast reads).
__global__ __launch_bounds__(256) void fused_node_kernel(
    const float* __restrict__ x, const unsigned* __restrict__ agg,
    const float* __restrict__ W_rel, const float* __restrict__ b_rel,
    const float* __restrict__ W_root, const float* __restrict__ lin_W,
    const float* __restrict__ lin_b, const float* __restrict__ gamma,
    const float* __restrict__ beta, float* __restrict__ out)
{
    __shared__ float agg_s[4][N_DIM];
    __shared__ float x_s[4][N_DIM];
    __shared__ float h_s[4][N_DIM];

    const int wave = threadIdx.x >> 6;
    const int lane = threadIdx.x & 63;
    const int node = blockIdx.x * 4 + wave;   // N % 4 == 0, always valid
    const int d0 = lane, d1 = lane + 64;
    const size_t base = (size_t)node * N_DIM;

    unsigned u0 = agg[base + d0], u1 = agg[base + d1];
    agg_s[wave][d0] = (u0 == ENC_NEG_INF) ? 0.0f : dec_f(u0);
    agg_s[wave][d1] = (u1 == ENC_NEG_INF) ? 0.0f : dec_f(u1);
    float xv0 = x[base + d0], xv1 = x[base + d1];
    x_s[wave][d0] = xv0;
    x_s[wave][d1] = xv1;
    __syncthreads();

    // ---- GEMM1: h = agg @ W_rel^T + b_rel + x @ W_root^T ----
    float acc0 = b_rel[d0], acc1 = b_rel[d1];
    const float4* wr0 = (const float4*)(W_rel  + (size_t)d0 * N_DIM);
    const float4* wr1 = (const float4*)(W_rel  + (size_t)d1 * N_DIM);
    const float4* wo0 = (const float4*)(W_root + (size_t)d0 * N_DIM);
    const float4* wo1 = (const float4*)(W_root + (size_t)d1 * N_DIM);
    const float4* as4 = (const float4*)agg_s[wave];
    const float4* xs4 = (const float4*)x_s[wave];
    #pragma unroll 8
    for (int k = 0; k < N_DIM / 4; k++) {
        float4 a = as4[k], xx = xs4[k];
        float4 r0 = wr0[k], r1 = wr1[k], o0 = wo0[k], o1 = wo1[k];
        acc0 += a.x*r0.x + a.y*r0.y + a.z*r0.z + a.w*r0.w
              + xx.x*o0.x + xx.y*o0.y + xx.z*o0.z + xx.w*o0.w;
        acc1 += a.x*r1.x + a.y*r1.y + a.z*r1.z + a.w*r1.w
              + xx.x*o1.x + xx.y*o1.y + xx.z*o1.z + xx.w*o1.w;
    }

    // ---- act + skip + LN #1 ----
    float h0 = gelu_exact(acc0) + xv0;
    float h1 = gelu_exact(acc1) + xv1;
    float s = h0 + h1;
    #pragma unroll
    for (int m = 32; m; m >>= 1) s += __shfl_xor(s, m);
    float mu = s * (1.0f / 128.0f);
    float dh0 = h0 - mu, dh1 = h1 - mu;
    float v = dh0 * dh0 + dh1 * dh1;
    #pragma unroll
    for (int m = 32; m; m >>= 1) v += __shfl_xor(v, m);
    float rstd = rsqrtf(v * (1.0f / 128.0f) + LN_EPS);
    float n0 = dh0 * rstd * gamma[d0] + beta[d0];
    float n1 = dh1 * rstd * gamma[d1] + beta[d1];

    // ---- GEMM2: t = n @ lin_W^T + lin_b ----
    h_s[wave][d0] = n0;
    h_s[wave][d1] = n1;
    __syncthreads();
    float b0 = lin_b[d0], b1 = lin_b[d1];
    const float4* lw0 = (const float4*)(lin_W + (size_t)d0 * N_DIM);
    const float4* lw1 = (const float4*)(lin_W + (size_t)d1 * N_DIM);
    const float4* hs4 = (const float4*)h_s[wave];
    #pragma unroll 8
    for (int k = 0; k < N_DIM / 4; k++) {
        float4 hh = hs4[k];
        float4 l0 = lw0[k], l1 = lw1[k];
        b0 += hh.x*l0.x + hh.y*l0.y + hh.z*l0.z + hh.w*l0.w;
        b1 += hh.x*l1.x + hh.y*l1.y + hh.z*l1.z + hh.w*l1.w;
    }

    // ---- act + skip + LN #2 ----
    float g0 = gelu_exact(b0) + n0;
    float g1 = gelu_exact(b1) + n1;
    float s2 = g0 + g1;
    #pragma unroll
    for (int m = 32; m; m >>= 1) s2 += __shfl_xor(s2, m);
    float mu2 = s2 * (1.0f / 128.0f);
    float e0 = g0 - mu2, e1 = g1 - mu2;
    float v2 = e0 * e0 + e1 * e1;
    #pragma unroll
    for (int m = 32; m; m >>= 1) v2 += __shfl_xor(v2, m);
    float rstd2 = rsqrtf(v2 * (1.0f / 128.0f) + LN_EPS);
    out[base + d0] = e0 * rstd2 * gamma[d0] + beta[d0];
    out[base + d1] = e1 * rstd2 * gamma[d1] + beta[d1];
}

extern "C" void kernel_launch(void* const* d_in, const int* in_sizes, int n_in,
                              void* d_out, int out_size, void* d_ws, size_t ws_size,
                              hipStream_t stream) {
    const float* x      = (const float*)d_in[0];
    const int*   ei     = (const int*)  d_in[1];   // [2, E] int32 (src row, dst row)
    const float* ew     = (const float*)d_in[2];
    const float* W_rel  = (const float*)d_in[3];
    const float* b_rel  = (const float*)d_in[4];
    const float* W_root = (const float*)d_in[5];
    const float* lin_W  = (const float*)d_in[6];
    const float* lin_b  = (const float*)d_in[7];
    const float* gamma  = (const float*)d_in[8];
    const float* beta   = (const float*)d_in[9];
    float* out = (float*)d_out;
    unsigned* agg = (unsigned*)d_ws;   // N*D uint32 = 10.24 MB

    // 1) init agg to enc(-inf)
    init_agg_kernel<<<(N_NODES * N_DIM / 4) / 256, 256, 0, stream>>>(agg);
    // 2) edge scatter-max (32 threads/edge, 4 dims each)
    scatter_max_kernel<<<(N_EDGES * 32) / 256, 256, 0, stream>>>(x, ei, ew, agg);
    // 3) fused per-node: GraphConv + gelu + skip + LN + Linear + gelu + skip + LN
    fused_node_kernel<<<N_NODES / 4, 256, 0, stream>>>(
        x, agg, W_rel, b_rel, W_root, lin_W, lin_b, gamma, beta, out);
    // 4) edge_weight passthrough (output 1)
    hipMemcpyAsync(out + (size_t)N_NODES * N_DIM, ew,
                   (size_t)N_EDGES * sizeof(float), hipMemcpyDeviceToDevice, stream);
}

// Round 2
// 694.973 us; speedup vs baseline: 1.9683x; 1.9683x over previous
//
#include <hip/hip_runtime.h>
#include <math.h>

#define N_NODES 20000
#define N_DIM   128
#define N_EDGES 640000
#define LN_EPS  1e-5f

__device__ __forceinline__ float gelu_exact(float v) {
    return 0.5f * v * (1.0f + erff(v * 0.70710678118654752f));
}

// ---------------- CSR build ----------------
__global__ void hist_kernel(const int* __restrict__ ei, int* __restrict__ deg) {
    int e = blockIdx.x * blockDim.x + threadIdx.x;
    if (e >= N_EDGES) return;
    atomicAdd(&deg[ei[N_EDGES + e]], 1);
}

__global__ __launch_bounds__(1024) void scan_kernel(const int* __restrict__ deg,
                                                    int* __restrict__ off,
                                                    int* __restrict__ cur) {
    __shared__ int sm[1024];
    const int t = threadIdx.x;
    const int lo = t * 20;
    const int hi = min(lo + 20, N_NODES);
    int s = 0;
    for (int i = lo; i < hi; i++) s += deg[i];
    sm[t] = s;
    __syncthreads();
    for (int d = 1; d < 1024; d <<= 1) {
        int v = (t >= d) ? sm[t - d] : 0;
        __syncthreads();
        sm[t] += v;
        __syncthreads();
    }
    int base = sm[t] - s;   // exclusive prefix
    for (int i = lo; i < hi; i++) {
        off[i] = base; cur[i] = base; base += deg[i];
    }
}

__global__ void fill_kernel(const int* __restrict__ ei, const float* __restrict__ ew,
                            int* __restrict__ cur, int* __restrict__ csr_src,
                            float* __restrict__ csr_w) {
    int e = blockIdx.x * blockDim.x + threadIdx.x;
    if (e >= N_EDGES) return;
    int dst = ei[N_EDGES + e];
    int pos = atomicAdd(&cur[dst], 1);
    csr_src[pos] = ei[e];
    csr_w[pos]   = ew[e];
}

// ---------------- fused per-node pipeline (gather-max + GraphConv + 2x GELU/LN) ----
// 1 wave per node, 4 waves per block. Lane owns dims d0=2*lane, d1=2*lane+1.
__global__ __launch_bounds__(256) void fused_node_kernel(
    const float* __restrict__ x,
    const int* __restrict__ off, const int* __restrict__ deg,
    const int* __restrict__ csr_src, const float* __restrict__ csr_w,
    const float* __restrict__ W_rel, const float* __restrict__ b_rel,
    const float* __restrict__ W_root, const float* __restrict__ lin_W,
    const float* __restrict__ lin_b, const float* __restrict__ gamma,
    const float* __restrict__ beta, float* __restrict__ out)
{
    __shared__ float agg_s[4][N_DIM];
    __shared__ float x_s[4][N_DIM];
    __shared__ float h_s[4][N_DIM];

    const int wave = threadIdx.x >> 6;
    const int lane = threadIdx.x & 63;
    const int node = blockIdx.x * 4 + wave;    // N % 4 == 0
    const int d0 = lane * 2, d1 = d0 + 1;
    const size_t base = (size_t)node * N_DIM;

    // ---- gather-side max aggregation ----
    const int start = off[node];
    const int dg    = deg[node];
    float m0 = -INFINITY, m1 = -INFINITY;
    for (int jb = 0; jb < dg; jb += 64) {
        int j = jb + lane;
        int   sv = 0; float wv = 0.0f;
        if (j < dg) { sv = csr_src[start + j]; wv = csr_w[start + j]; }
        int cnt = min(64, dg - jb);
        for (int i = 0; i < cnt; i++) {
            int   src = __shfl(sv, i);
            float w   = __shfl(wv, i);
            float2 xv = *(const float2*)(x + (size_t)src * N_DIM + d0);
            m0 = fmaxf(m0, xv.x * w);
            m1 = fmaxf(m1, xv.y * w);
        }
    }
    // empty segment -> 0 (PyG fill); nonempty segments are finite
    if (dg == 0) { m0 = 0.0f; m1 = 0.0f; }

    float2 xv2 = ((const float2*)(x + base))[lane];
    ((float2*)agg_s[wave])[lane] = make_float2(m0, m1);
    ((float2*)x_s[wave])[lane]   = xv2;
    __syncthreads();

    // ---- GEMM1: h = agg @ W_rel^T + b_rel + x @ W_root^T ----
    float2 br = ((const float2*)b_rel)[lane];
    float acc0 = br.x, acc1 = br.y;
    const float4* wr0 = (const float4*)(W_rel  + (size_t)d0 * N_DIM);
    const float4* wr1 = (const float4*)(W_rel  + (size_t)d1 * N_DIM);
    const float4* wo0 = (const float4*)(W_root + (size_t)d0 * N_DIM);
    const float4* wo1 = (const float4*)(W_root + (size_t)d1 * N_DIM);
    const float4* as4 = (const float4*)agg_s[wave];
    const float4* xs4 = (const float4*)x_s[wave];
    #pragma unroll 8
    for (int k = 0; k < N_DIM / 4; k++) {
        float4 a = as4[k], xx = xs4[k];
        float4 r0 = wr0[k], r1 = wr1[k], o0 = wo0[k], o1 = wo1[k];
        acc0 += a.x*r0.x + a.y*r0.y + a.z*r0.z + a.w*r0.w
              + xx.x*o0.x + xx.y*o0.y + xx.z*o0.z + xx.w*o0.w;
        acc1 += a.x*r1.x + a.y*r1.y + a.z*r1.z + a.w*r1.w
              + xx.x*o1.x + xx.y*o1.y + xx.z*o1.z + xx.w*o1.w;
    }

    // ---- act + skip + LN #1 ----
    float h0 = gelu_exact(acc0) + xv2.x;
    float h1 = gelu_exact(acc1) + xv2.y;
    float s = h0 + h1;
    #pragma unroll
    for (int m = 32; m; m >>= 1) s += __shfl_xor(s, m);
    float mu = s * (1.0f / 128.0f);
    float dh0 = h0 - mu, dh1 = h1 - mu;
    float v = dh0 * dh0 + dh1 * dh1;
    #pragma unroll
    for (int m = 32; m; m >>= 1) v += __shfl_xor(v, m);
    float rstd = rsqrtf(v * (1.0f / 128.0f) + LN_EPS);
    float2 gm = ((const float2*)gamma)[lane];
    float2 bt = ((const float2*)beta)[lane];
    float n0 = dh0 * rstd * gm.x + bt.x;
    float n1 = dh1 * rstd * gm.y + bt.y;

    // ---- GEMM2: t = n @ lin_W^T + lin_b ----
    ((float2*)h_s[wave])[lane] = make_float2(n0, n1);
    __syncthreads();
    float2 lb = ((const float2*)lin_b)[lane];
    float b0 = lb.x, b1 = lb.y;
    const float4* lw0 = (const float4*)(lin_W + (size_t)d0 * N_DIM);
    const float4* lw1 = (const float4*)(lin_W + (size_t)d1 * N_DIM);
    const float4* hs4 = (const float4*)h_s[wave];
    #pragma unroll 8
    for (int k = 0; k < N_DIM / 4; k++) {
        float4 hh = hs4[k];
        float4 l0 = lw0[k], l1 = lw1[k];
        b0 += hh.x*l0.x + hh.y*l0.y + hh.z*l0.z + hh.w*l0.w;
        b1 += hh.x*l1.x + hh.y*l1.y + hh.z*l1.z + hh.w*l1.w;
    }

    // ---- act + skip + LN #2 ----
    float g0 = gelu_exact(b0) + n0;
    float g1 = gelu_exact(b1) + n1;
    float s2 = g0 + g1;
    #pragma unroll
    for (int m = 32; m; m >>= 1) s2 += __shfl_xor(s2, m);
    float mu2 = s2 * (1.0f / 128.0f);
    float e0 = g0 - mu2, e1 = g1 - mu2;
    float v2 = e0 * e0 + e1 * e1;
    #pragma unroll
    for (int m = 32; m; m >>= 1) v2 += __shfl_xor(v2, m);
    float rstd2 = rsqrtf(v2 * (1.0f / 128.0f) + LN_EPS);
    float o0 = e0 * rstd2 * gm.x + bt.x;
    float o1 = e1 * rstd2 * gm.y + bt.y;
    ((float2*)(out + base))[lane] = make_float2(o0, o1);
}

extern "C" void kernel_launch(void* const* d_in, const int* in_sizes, int n_in,
                              void* d_out, int out_size, void* d_ws, size_t ws_size,
                              hipStream_t stream) {
    const float* x      = (const float*)d_in[0];
    const int*   ei     = (const int*)  d_in[1];   // [2, E] int32
    const float* ew     = (const float*)d_in[2];
    const float* W_rel  = (const float*)d_in[3];
    const float* b_rel  = (const float*)d_in[4];
    const float* W_root = (const float*)d_in[5];
    const float* lin_W  = (const float*)d_in[6];
    const float* lin_b  = (const float*)d_in[7];
    const float* gamma  = (const float*)d_in[8];
    const float* beta   = (const float*)d_in[9];
    float* out = (float*)d_out;

    // ws layout: deg[N] | off[N] | cur[N] | csr_src[E] | csr_w[E]  (~5.4 MB)
    int*   deg     = (int*)d_ws;
    int*   off     = deg + N_NODES;
    int*   cur     = off + N_NODES;
    int*   csr_src = cur + N_NODES;
    float* csr_w   = (float*)(csr_src + N_EDGES);

    hipMemsetAsync(deg, 0, N_NODES * sizeof(int), stream);
    hist_kernel<<<(N_EDGES + 255) / 256, 256, 0, stream>>>(ei, deg);
    scan_kernel<<<1, 1024, 0, stream>>>(deg, off, cur);
    fill_kernel<<<(N_EDGES + 255) / 256, 256, 0, stream>>>(ei, ew, cur, csr_src, csr_w);
    fused_node_kernel<<<N_NODES / 4, 256, 0, stream>>>(
        x, off, deg, csr_src, csr_w,
        W_rel, b_rel, W_root, lin_W, lin_b, gamma, beta, out);
    hipMemcpyAsync(out + (size_t)N_NODES * N_DIM, ew,
                   (size_t)N_EDGES * sizeof(float), hipMemcpyDeviceToDevice, stream);
}

// Round 3
// 651.518 us; speedup vs baseline: 2.0996x; 1.0667x over previous
//
#include <hip/hip_runtime.h>
#include <math.h>

#define N_NODES 20000
#define N_DIM   128
#define N_EDGES 640000
#define LN_EPS  1e-5f

__device__ __forceinline__ float gelu_exact(float v) {
    return 0.5f * v * (1.0f + erff(v * 0.70710678118654752f));
}

// ---------------- CSR build ----------------
__global__ void hist_kernel(const int* __restrict__ ei, int* __restrict__ deg) {
    int e = blockIdx.x * blockDim.x + threadIdx.x;
    if (e >= N_EDGES) return;
    atomicAdd(&deg[ei[N_EDGES + e]], 1);
}

__global__ __launch_bounds__(1024) void scan_kernel(const int* __restrict__ deg,
                                                    int* __restrict__ off,
                                                    int* __restrict__ cur) {
    __shared__ int sm[1024];
    const int t = threadIdx.x;
    const int lo = t * 20;
    const int hi = min(lo + 20, N_NODES);
    int s = 0;
    for (int i = lo; i < hi; i++) s += deg[i];
    sm[t] = s;
    __syncthreads();
    for (int d = 1; d < 1024; d <<= 1) {
        int v = (t >= d) ? sm[t - d] : 0;
        __syncthreads();
        sm[t] += v;
        __syncthreads();
    }
    int base = sm[t] - s;   // exclusive prefix
    for (int i = lo; i < hi; i++) {
        off[i] = base; cur[i] = base; base += deg[i];
    }
}

__global__ void fill_kernel(const int* __restrict__ ei, const float* __restrict__ ew,
                            int* __restrict__ cur, int2* __restrict__ csr) {
    int e = blockIdx.x * blockDim.x + threadIdx.x;
    if (e >= N_EDGES) return;
    int dst = ei[N_EDGES + e];
    int pos = atomicAdd(&cur[dst], 1);
    csr[pos] = make_int2(ei[e], __float_as_int(ew[e]));
}

// ---------------- fused per-node pipeline (gather-max + GraphConv + 2x GELU/LN) ----
// 1 wave per node, 4 waves per block. Lane owns dims d0=2*lane, d1=2*lane+1.
__global__ __launch_bounds__(256) void fused_node_kernel(
    const float* __restrict__ x,
    const int* __restrict__ off, const int* __restrict__ deg,
    const int2* __restrict__ csr,
    const float* __restrict__ W_rel, const float* __restrict__ b_rel,
    const float* __restrict__ W_root, const float* __restrict__ lin_W,
    const float* __restrict__ lin_b, const float* __restrict__ gamma,
    const float* __restrict__ beta, float* __restrict__ out)
{
    __shared__ float agg_s[4][N_DIM];
    __shared__ float x_s[4][N_DIM];
    __shared__ float h_s[4][N_DIM];

    const int wave = threadIdx.x >> 6;
    const int lane = threadIdx.x & 63;
    const int node = blockIdx.x * 4 + wave;    // N % 4 == 0
    const int d0 = lane * 2;
    const size_t base = (size_t)node * N_DIM;

    // ---- gather-side max aggregation, 8-edge batches, wave-uniform indexing ----
    const int start = __builtin_amdgcn_readfirstlane(off[node]);
    const int dg    = __builtin_amdgcn_readfirstlane(deg[node]);
    float m0 = -INFINITY, m1 = -INFINITY;
    for (int j = 0; j < dg; j += 8) {
        int2 ev[8];
        #pragma unroll
        for (int k = 0; k < 8; k++) {
            int idx = j + k;
            ev[k] = csr[start + ((idx < dg) ? idx : 0)];
        }
        float2 xv[8];
        #pragma unroll
        for (int k = 0; k < 8; k++)
            xv[k] = *(const float2*)(x + (size_t)ev[k].x * N_DIM + d0);
        #pragma unroll
        for (int k = 0; k < 8; k++) {
            if (j + k < dg) {
                float w = __int_as_float(ev[k].y);
                m0 = fmaxf(m0, xv[k].x * w);
                m1 = fmaxf(m1, xv[k].y * w);
            }
        }
    }
    // empty segment -> 0 (PyG fill); nonempty segments are finite
    if (dg == 0) { m0 = 0.0f; m1 = 0.0f; }

    float2 xv2 = ((const float2*)(x + base))[lane];
    ((float2*)agg_s[wave])[lane] = make_float2(m0, m1);
    ((float2*)x_s[wave])[lane]   = xv2;
    __syncthreads();

    // ---- GEMM1: h = agg @ W_rel^T + b_rel + x @ W_root^T ----
    float2 br = ((const float2*)b_rel)[lane];
    float acc0 = br.x, acc1 = br.y;
    const int d1r = d0 + 1;
    const float4* wr0 = (const float4*)(W_rel  + (size_t)d0  * N_DIM);
    const float4* wr1 = (const float4*)(W_rel  + (size_t)d1r * N_DIM);
    const float4* wo0 = (const float4*)(W_root + (size_t)d0  * N_DIM);
    const float4* wo1 = (const float4*)(W_root + (size_t)d1r * N_DIM);
    const float4* as4 = (const float4*)agg_s[wave];
    const float4* xs4 = (const float4*)x_s[wave];
    #pragma unroll 8
    for (int k = 0; k < N_DIM / 4; k++) {
        float4 a = as4[k], xx = xs4[k];
        float4 r0 = wr0[k], r1 = wr1[k], o0 = wo0[k], o1 = wo1[k];
        acc0 += a.x*r0.x + a.y*r0.y + a.z*r0.z + a.w*r0.w
              + xx.x*o0.x + xx.y*o0.y + xx.z*o0.z + xx.w*o0.w;
        acc1 += a.x*r1.x + a.y*r1.y + a.z*r1.z + a.w*r1.w
              + xx.x*o1.x + xx.y*o1.y + xx.z*o1.z + xx.w*o1.w;
    }

    // ---- act + skip + LN #1 ----
    float h0 = gelu_exact(acc0) + xv2.x;
    float h1 = gelu_exact(acc1) + xv2.y;
    float s = h0 + h1;
    #pragma unroll
    for (int m = 32; m; m >>= 1) s += __shfl_xor(s, m);
    float mu = s * (1.0f / 128.0f);
    float dh0 = h0 - mu, dh1 = h1 - mu;
    float v = dh0 * dh0 + dh1 * dh1;
    #pragma unroll
    for (int m = 32; m; m >>= 1) v += __shfl_xor(v, m);
    float rstd = rsqrtf(v * (1.0f / 128.0f) + LN_EPS);
    float2 gm = ((const float2*)gamma)[lane];
    float2 bt = ((const float2*)beta)[lane];
    float n0 = dh0 * rstd * gm.x + bt.x;
    float n1 = dh1 * rstd * gm.y + bt.y;

    // ---- GEMM2: t = n @ lin_W^T + lin_b ----
    ((float2*)h_s[wave])[lane] = make_float2(n0, n1);
    __syncthreads();
    float2 lb = ((const float2*)lin_b)[lane];
    float b0 = lb.x, b1 = lb.y;
    const float4* lw0 = (const float4*)(lin_W + (size_t)d0  * N_DIM);
    const float4* lw1 = (const float4*)(lin_W + (size_t)d1r * N_DIM);
    const float4* hs4 = (const float4*)h_s[wave];
    #pragma unroll 8
    for (int k = 0; k < N_DIM / 4; k++) {
        float4 hh = hs4[k];
        float4 l0 = lw0[k], l1 = lw1[k];
        b0 += hh.x*l0.x + hh.y*l0.y + hh.z*l0.z + hh.w*l0.w;
        b1 += hh.x*l1.x + hh.y*l1.y + hh.z*l1.z + hh.w*l1.w;
    }

    // ---- act + skip + LN #2 ----
    float g0 = gelu_exact(b0) + n0;
    float g1 = gelu_exact(b1) + n1;
    float s2 = g0 + g1;
    #pragma unroll
    for (int m = 32; m; m >>= 1) s2 += __shfl_xor(s2, m);
    float mu2 = s2 * (1.0f / 128.0f);
    float e0 = g0 - mu2, e1 = g1 - mu2;
    float v2 = e0 * e0 + e1 * e1;
    #pragma unroll
    for (int m = 32; m; m >>= 1) v2 += __shfl_xor(v2, m);
    float rstd2 = rsqrtf(v2 * (1.0f / 128.0f) + LN_EPS);
    float o0 = e0 * rstd2 * gm.x + bt.x;
    float o1 = e1 * rstd2 * gm.y + bt.y;
    ((float2*)(out + base))[lane] = make_float2(o0, o1);
}

extern "C" void kernel_launch(void* const* d_in, const int* in_sizes, int n_in,
                              void* d_out, int out_size, void* d_ws, size_t ws_size,
                              hipStream_t stream) {
    const float* x      = (const float*)d_in[0];
    const int*   ei     = (const int*)  d_in[1];   // [2, E] int32
    const float* ew     = (const float*)d_in[2];
    const float* W_rel  = (const float*)d_in[3];
    const float* b_rel  = (const float*)d_in[4];
    const float* W_root = (const float*)d_in[5];
    const float* lin_W  = (const float*)d_in[6];
    const float* lin_b  = (const float*)d_in[7];
    const float* gamma  = (const float*)d_in[8];
    const float* beta   = (const float*)d_in[9];
    float* out = (float*)d_out;

    // ws layout: deg[N] | off[N] | cur[N] | csr int2[E]  (~5.4 MB)
    int*  deg = (int*)d_ws;
    int*  off = deg + N_NODES;
    int*  cur = off + N_NODES;
    int2* csr = (int2*)(cur + N_NODES);

    hipMemsetAsync(deg, 0, N_NODES * sizeof(int), stream);
    hist_kernel<<<(N_EDGES + 255) / 256, 256, 0, stream>>>(ei, deg);
    scan_kernel<<<1, 1024, 0, stream>>>(deg, off, cur);
    fill_kernel<<<(N_EDGES + 255) / 256, 256, 0, stream>>>(ei, ew, cur, csr);
    fused_node_kernel<<<N_NODES / 4, 256, 0, stream>>>(
        x, off, deg, csr,
        W_rel, b_rel, W_root, lin_W, lin_b, gamma, beta, out);
    hipMemcpyAsync(out + (size_t)N_NODES * N_DIM, ew,
                   (size_t)N_EDGES * sizeof(float), hipMemcpyDeviceToDevice, stream);
}

// Round 4
// 302.137 us; speedup vs baseline: 4.5275x; 2.1564x over previous
//
#include <hip/hip_runtime.h>
#include <math.h>

#define N_NODES 20000
#define N_DIM   128
#define N_EDGES 640000
#define LN_EPS  1e-5f
#define NPW 4              // nodes per wave
#define NPB 16             // nodes per block (4 waves)

__device__ __forceinline__ float gelu_exact(float v) {
    return 0.5f * v * (1.0f + erff(v * 0.70710678118654752f));
}

// ---------------- CSR build ----------------
__global__ void hist_kernel(const int* __restrict__ ei, int* __restrict__ deg) {
    int e = blockIdx.x * blockDim.x + threadIdx.x;
    if (e >= N_EDGES) return;
    atomicAdd(&deg[ei[N_EDGES + e]], 1);
}

__global__ __launch_bounds__(1024) void scan_kernel(const int* __restrict__ deg,
                                                    int* __restrict__ off,
                                                    int* __restrict__ cur) {
    __shared__ int sm[1024];
    const int t = threadIdx.x;
    const int lo = t * 20;
    const int hi = min(lo + 20, N_NODES);
    int s = 0;
    for (int i = lo; i < hi; i++) s += deg[i];
    sm[t] = s;
    __syncthreads();
    for (int d = 1; d < 1024; d <<= 1) {
        int v = (t >= d) ? sm[t - d] : 0;
        __syncthreads();
        sm[t] += v;
        __syncthreads();
    }
    int base = sm[t] - s;   // exclusive prefix
    for (int i = lo; i < hi; i++) {
        off[i] = base; cur[i] = base; base += deg[i];
    }
}

__global__ void fill_kernel(const int* __restrict__ ei, const float* __restrict__ ew,
                            int* __restrict__ cur, int2* __restrict__ csr) {
    int e = blockIdx.x * blockDim.x + threadIdx.x;
    if (e >= N_EDGES) return;
    int dst = ei[N_EDGES + e];
    int pos = atomicAdd(&cur[dst], 1);
    csr[pos] = make_int2(ei[e], __float_as_int(ew[e]));
}

// ---------------- weight transpose: Wt[m][k][d] = W_m[d][k] ----------------
__global__ void transpose_w_kernel(const float* __restrict__ Wr,
                                   const float* __restrict__ Wo,
                                   const float* __restrict__ Wl,
                                   float* __restrict__ Wt) {
    int t = blockIdx.x * blockDim.x + threadIdx.x;   // 3*128*128 threads
    int m = t >> 14;
    int rem = t & 16383;
    int k = rem >> 7;
    int d = rem & 127;
    const float* W = (m == 0) ? Wr : ((m == 1) ? Wo : Wl);
    Wt[t] = W[d * N_DIM + k];
}

// ---------------- fused per-node pipeline ----------------
// 4 waves/block, 4 nodes/wave. Lane owns dims d0=2*lane, d0+1 per node.
// Weights read from global TRANSPOSED (coalesced); node vectors via per-wave
// LDS rows (same-address broadcast reads). No cross-wave sharing -> no barriers.
__global__ __launch_bounds__(256) void fused_node_kernel(
    const float* __restrict__ x,
    const int* __restrict__ off, const int* __restrict__ deg,
    const int2* __restrict__ csr,
    const float* __restrict__ Wt,        // [3][128][128]
    const float* __restrict__ b_rel,
    const float* __restrict__ lin_b, const float* __restrict__ gamma,
    const float* __restrict__ beta, float* __restrict__ out)
{
    __shared__ float agg_s[NPB][N_DIM];
    __shared__ float x_s[NPB][N_DIM];
    __shared__ float h_s[NPB][N_DIM];

    const int wave = threadIdx.x >> 6;
    const int lane = threadIdx.x & 63;
    const int d0 = lane * 2;
    const int ln = wave * NPW;                 // block-local base row
    const int nb = blockIdx.x * NPB + ln;      // global base node

    // ---- gather-max for 4 nodes (8-edge ILP batches) ----
    float2 xsv[NPW];
    for (int r = 0; r < NPW; r++) {
        const int node = nb + r;
        const int start = __builtin_amdgcn_readfirstlane(off[node]);
        const int dg    = __builtin_amdgcn_readfirstlane(deg[node]);
        float m0 = -INFINITY, m1 = -INFINITY;
        for (int j = 0; j < dg; j += 8) {
            int2 ev[8];
            #pragma unroll
            for (int k = 0; k < 8; k++) {
                int idx = j + k;
                ev[k] = csr[start + ((idx < dg) ? idx : 0)];
            }
            float2 xv[8];
            #pragma unroll
            for (int k = 0; k < 8; k++)
                xv[k] = *(const float2*)(x + (size_t)ev[k].x * N_DIM + d0);
            #pragma unroll
            for (int k = 0; k < 8; k++) {
                if (j + k < dg) {
                    float w = __int_as_float(ev[k].y);
                    m0 = fmaxf(m0, xv[k].x * w);
                    m1 = fmaxf(m1, xv[k].y * w);
                }
            }
        }
        if (dg == 0) { m0 = 0.0f; m1 = 0.0f; }
        ((float2*)agg_s[ln + r])[lane] = make_float2(m0, m1);
        float2 xr = ((const float2*)(x + (size_t)node * N_DIM))[lane];
        ((float2*)x_s[ln + r])[lane] = xr;
        xsv[r] = xr;
    }

    const float* WtR = Wt;
    const float* WtO = Wt + N_DIM * N_DIM;
    const float* WtL = Wt + 2 * N_DIM * N_DIM;

    // ---- GEMM1: h = agg @ W_rel^T + b_rel + x @ W_root^T ----
    float2 br = ((const float2*)b_rel)[lane];
    float2 acc[NPW];
    #pragma unroll
    for (int r = 0; r < NPW; r++) acc[r] = br;

    #pragma unroll 2
    for (int kg = 0; kg < N_DIM / 4; kg++) {
        const int k = kg * 4;
        float2 wr[4], wo[4];
        #pragma unroll
        for (int i = 0; i < 4; i++) {
            wr[i] = *(const float2*)(WtR + (k + i) * N_DIM + d0);
            wo[i] = *(const float2*)(WtO + (k + i) * N_DIM + d0);
        }
        #pragma unroll
        for (int r = 0; r < NPW; r++) {
            float4 av = *(const float4*)(agg_s[ln + r] + k);
            float4 xv = *(const float4*)(x_s[ln + r] + k);
            acc[r].x += av.x*wr[0].x + av.y*wr[1].x + av.z*wr[2].x + av.w*wr[3].x
                      + xv.x*wo[0].x + xv.y*wo[1].x + xv.z*wo[2].x + xv.w*wo[3].x;
            acc[r].y += av.x*wr[0].y + av.y*wr[1].y + av.z*wr[2].y + av.w*wr[3].y
                      + xv.x*wo[0].y + xv.y*wo[1].y + xv.z*wo[2].y + xv.w*wo[3].y;
        }
    }

    // ---- act + skip + LN #1 (4 interleaved wave reductions) ----
    float2 gm = ((const float2*)gamma)[lane];
    float2 bt = ((const float2*)beta)[lane];
    float h0[NPW], h1[NPW], s[NPW];
    #pragma unroll
    for (int r = 0; r < NPW; r++) {
        h0[r] = gelu_exact(acc[r].x) + xsv[r].x;
        h1[r] = gelu_exact(acc[r].y) + xsv[r].y;
        s[r] = h0[r] + h1[r];
    }
    #pragma unroll
    for (int m = 32; m; m >>= 1)
        #pragma unroll
        for (int r = 0; r < NPW; r++) s[r] += __shfl_xor(s[r], m);
    float v[NPW];
    #pragma unroll
    for (int r = 0; r < NPW; r++) {
        float mu = s[r] * (1.0f / 128.0f);
        h0[r] -= mu; h1[r] -= mu;
        v[r] = h0[r] * h0[r] + h1[r] * h1[r];
    }
    #pragma unroll
    for (int m = 32; m; m >>= 1)
        #pragma unroll
        for (int r = 0; r < NPW; r++) v[r] += __shfl_xor(v[r], m);
    float2 nrm[NPW];
    #pragma unroll
    for (int r = 0; r < NPW; r++) {
        float rstd = rsqrtf(v[r] * (1.0f / 128.0f) + LN_EPS);
        nrm[r].x = h0[r] * rstd * gm.x + bt.x;
        nrm[r].y = h1[r] * rstd * gm.y + bt.y;
        ((float2*)h_s[ln + r])[lane] = nrm[r];
    }

    // ---- GEMM2: t = n @ lin_W^T + lin_b ----
    float2 lb = ((const float2*)lin_b)[lane];
    float2 acc2[NPW];
    #pragma unroll
    for (int r = 0; r < NPW; r++) acc2[r] = lb;

    #pragma unroll 2
    for (int kg = 0; kg < N_DIM / 4; kg++) {
        const int k = kg * 4;
        float2 wl[4];
        #pragma unroll
        for (int i = 0; i < 4; i++)
            wl[i] = *(const float2*)(WtL + (k + i) * N_DIM + d0);
        #pragma unroll
        for (int r = 0; r < NPW; r++) {
            float4 hv = *(const float4*)(h_s[ln + r] + k);
            acc2[r].x += hv.x*wl[0].x + hv.y*wl[1].x + hv.z*wl[2].x + hv.w*wl[3].x;
            acc2[r].y += hv.x*wl[0].y + hv.y*wl[1].y + hv.z*wl[2].y + hv.w*wl[3].y;
        }
    }

    // ---- act + skip + LN #2 + store ----
    float g0[NPW], g1[NPW];
    #pragma unroll
    for (int r = 0; r < NPW; r++) {
        g0[r] = gelu_exact(acc2[r].x) + nrm[r].x;
        g1[r] = gelu_exact(acc2[r].y) + nrm[r].y;
        s[r] = g0[r] + g1[r];
    }
    #pragma unroll
    for (int m = 32; m; m >>= 1)
        #pragma unroll
        for (int r = 0; r < NPW; r++) s[r] += __shfl_xor(s[r], m);
    #pragma unroll
    for (int r = 0; r < NPW; r++) {
        float mu = s[r] * (1.0f / 128.0f);
        g0[r] -= mu; g1[r] -= mu;
        v[r] = g0[r] * g0[r] + g1[r] * g1[r];
    }
    #pragma unroll
    for (int m = 32; m; m >>= 1)
        #pragma unroll
        for (int r = 0; r < NPW; r++) v[r] += __shfl_xor(v[r], m);
    #pragma unroll
    for (int r = 0; r < NPW; r++) {
        float rstd = rsqrtf(v[r] * (1.0f / 128.0f) + LN_EPS);
        float o0 = g0[r] * rstd * gm.x + bt.x;
        float o1 = g1[r] * rstd * gm.y + bt.y;
        ((float2*)(out + (size_t)(nb + r) * N_DIM))[lane] = make_float2(o0, o1);
    }
}

extern "C" void kernel_launch(void* const* d_in, const int* in_sizes, int n_in,
                              void* d_out, int out_size, void* d_ws, size_t ws_size,
                              hipStream_t stream) {
    const float* x      = (const float*)d_in[0];
    const int*   ei     = (const int*)  d_in[1];   // [2, E] int32
    const float* ew     = (const float*)d_in[2];
    const float* W_rel  = (const float*)d_in[3];
    const float* b_rel  = (const float*)d_in[4];
    const float* W_root = (const float*)d_in[5];
    const float* lin_W  = (const float*)d_in[6];
    const float* lin_b  = (const float*)d_in[7];
    const float* gamma  = (const float*)d_in[8];
    const float* beta   = (const float*)d_in[9];
    float* out = (float*)d_out;

    // ws layout: deg[N] | off[N] | cur[N] | csr int2[E] | Wt[3*128*128]
    int*   deg = (int*)d_ws;
    int*   off = deg + N_NODES;
    int*   cur = off + N_NODES;
    int2*  csr = (int2*)(cur + N_NODES);
    float* Wt  = (float*)(csr + N_EDGES);

    hipMemsetAsync(deg, 0, N_NODES * sizeof(int), stream);
    transpose_w_kernel<<<(3 * N_DIM * N_DIM) / 256, 256, 0, stream>>>(W_rel, W_root, lin_W, Wt);
    hist_kernel<<<(N_EDGES + 255) / 256, 256, 0, stream>>>(ei, deg);
    scan_kernel<<<1, 1024, 0, stream>>>(deg, off, cur);
    fill_kernel<<<(N_EDGES + 255) / 256, 256, 0, stream>>>(ei, ew, cur, csr);
    fused_node_kernel<<<N_NODES / NPB, 256, 0, stream>>>(
        x, off, deg, csr, Wt, b_rel, lin_b, gamma, beta, out);
    hipMemcpyAsync(out + (size_t)N_NODES * N_DIM, ew,
                   (size_t)N_EDGES * sizeof(float), hipMemcpyDeviceToDevice, stream);
}

// Round 5
// 230.426 us; speedup vs baseline: 5.9365x; 1.3112x over previous
//
#include <hip/hip_runtime.h>
#include <math.h>

#define N_NODES 20000
#define N_DIM   128
#define N_EDGES 640000
#define LN_EPS  1e-5f
#define NPW 4              // nodes per wave; 1 wave per block

__device__ __forceinline__ float gelu_exact(float v) {
    return 0.5f * v * (1.0f + erff(v * 0.70710678118654752f));
}
__device__ __forceinline__ float2 fma2(float s, float2 w, float2 a) {
    a.x = fmaf(s, w.x, a.x);
    a.y = fmaf(s, w.y, a.y);
    return a;
}

// ---------------- prep: ew copy + weight repack + deg zero (one dispatch) ----
// Weight layout Wp[m][kp][p] (float4), kp=k/2, p=d/2:
//   {W[2p][2kp], W[2p+1][2kp], W[2p][2kp+1], W[2p+1][2kp+1]}  (W row-major [d][k])
#define TASK_A 160000                 // ew float4 copies
#define TASK_B 12288                  // 3*64*64 weight quads
#define TASK_C 5000                   // deg int4 zeros
__global__ __launch_bounds__(256) void prep_kernel(
    const float* __restrict__ ew, float* __restrict__ out_ew,
    const float* __restrict__ Wr, const float* __restrict__ Wo,
    const float* __restrict__ Wl, float4* __restrict__ Wp,
    int4* __restrict__ deg4)
{
    int t = blockIdx.x * blockDim.x + threadIdx.x;
    if (t < TASK_A) {
        ((float4*)out_ew)[t] = ((const float4*)ew)[t];
    } else if (t < TASK_A + TASK_B) {
        int u = t - TASK_A;
        int m = u >> 12, r = u & 4095;
        int kp = r >> 6, p = r & 63;
        const float* W = (m == 0) ? Wr : ((m == 1) ? Wo : Wl);
        float4 v;
        v.x = W[(2*p)     * N_DIM + 2*kp];
        v.y = W[(2*p + 1) * N_DIM + 2*kp];
        v.z = W[(2*p)     * N_DIM + 2*kp + 1];
        v.w = W[(2*p + 1) * N_DIM + 2*kp + 1];
        Wp[u] = v;
    } else if (t < TASK_A + TASK_B + TASK_C) {
        deg4[t - TASK_A - TASK_B] = make_int4(0, 0, 0, 0);
    }
}

// ---------------- CSR build ----------------
__global__ void hist_kernel(const int* __restrict__ ei, int* __restrict__ deg) {
    int t = blockIdx.x * blockDim.x + threadIdx.x;   // N_EDGES/4 threads
    int4 d = ((const int4*)(ei + N_EDGES))[t];
    atomicAdd(&deg[d.x], 1);
    atomicAdd(&deg[d.y], 1);
    atomicAdd(&deg[d.z], 1);
    atomicAdd(&deg[d.w], 1);
}

__global__ __launch_bounds__(1024) void scan_kernel(const int* __restrict__ deg,
                                                    int* __restrict__ off,
                                                    int* __restrict__ cur) {
    __shared__ int sm[1024];
    const int t = threadIdx.x;
    const int lo = t * 20;                 // 20000 = 1000 * 20 exactly
    int4 d4[5];
    int s = 0;
    if (lo < N_NODES) {
        #pragma unroll
        for (int i = 0; i < 5; i++) {
            d4[i] = ((const int4*)(deg + lo))[i];
            s += d4[i].x + d4[i].y + d4[i].z + d4[i].w;
        }
    }
    sm[t] = s;
    __syncthreads();
    for (int d = 1; d < 1024; d <<= 1) {
        int v = (t >= d) ? sm[t - d] : 0;
        __syncthreads();
        sm[t] += v;
        __syncthreads();
    }
    if (lo < N_NODES) {
        int base = sm[t] - s;              // exclusive prefix
        #pragma unroll
        for (int i = 0; i < 5; i++) {
            int4 o;
            o.x = base; base += d4[i].x;
            o.y = base; base += d4[i].y;
            o.z = base; base += d4[i].z;
            o.w = base; base += d4[i].w;
            ((int4*)(off + lo))[i] = o;
            ((int4*)(cur + lo))[i] = o;
        }
    }
}

__global__ void fill_kernel(const int* __restrict__ ei, const float* __restrict__ ew,
                            int* __restrict__ cur, int2* __restrict__ csr) {
    int e = blockIdx.x * blockDim.x + threadIdx.x;
    if (e >= N_EDGES) return;
    int dst = ei[N_EDGES + e];
    int pos = atomicAdd(&cur[dst], 1);
    csr[pos] = make_int2(ei[e] << 9, __float_as_int(ew[e]));   // byte offset of x row
}

// ---------------- fused per-node pipeline ----------------
// 1 wave per block, 4 nodes per wave. Lane owns dims d0=2*lane, d0+1.
// No __syncthreads anywhere (single wave). Weights read coalesced (Wp quads).
__global__ __launch_bounds__(64) void fused_node_kernel(
    const float* __restrict__ x,
    const int* __restrict__ off, const int* __restrict__ deg,
    const int2* __restrict__ csr,
    const float4* __restrict__ Wp,       // [3][64][64]
    const float* __restrict__ b_rel,
    const float* __restrict__ lin_b, const float* __restrict__ gamma,
    const float* __restrict__ beta, float* __restrict__ out)
{
    __shared__ float agg_s[NPW][N_DIM];   // reused for normalized h before GEMM2
    __shared__ float x_s[NPW][N_DIM];

    const int lane = threadIdx.x & 63;
    const int nb = blockIdx.x * NPW;
    const int lane8 = lane << 3;          // byte offset of this lane's float2
    const char* xb = (const char*)x;

    // ---- gather-max for 4 nodes (8-edge ILP batches, tail predicated) ----
    float2 xsv[NPW];
    for (int r = 0; r < NPW; r++) {
        const int node = nb + r;
        const int start = __builtin_amdgcn_readfirstlane(off[node]);
        const int dg    = __builtin_amdgcn_readfirstlane(deg[node]);
        float m0 = -INFINITY, m1 = -INFINITY;
        const int nb8 = dg & ~7;
        for (int j = 0; j < nb8; j += 8) {
            int2 ev[8];
            #pragma unroll
            for (int k = 0; k < 8; k++) ev[k] = csr[start + j + k];
            float2 xv[8];
            #pragma unroll
            for (int k = 0; k < 8; k++)
                xv[k] = *(const float2*)(xb + (size_t)(unsigned)ev[k].x + lane8);
            #pragma unroll
            for (int k = 0; k < 8; k++) {
                float w = __int_as_float(ev[k].y);
                m0 = fmaxf(m0, xv[k].x * w);
                m1 = fmaxf(m1, xv[k].y * w);
            }
        }
        const int rem = dg - nb8;
        if (rem) {
            int2 ev[8];
            #pragma unroll
            for (int k = 0; k < 8; k++)
                ev[k] = csr[start + ((k < rem) ? nb8 + k : 0)];
            float2 xv[8];
            #pragma unroll
            for (int k = 0; k < 8; k++)
                xv[k] = *(const float2*)(xb + (size_t)(unsigned)ev[k].x + lane8);
            #pragma unroll
            for (int k = 0; k < 8; k++) {
                if (k < rem) {
                    float w = __int_as_float(ev[k].y);
                    m0 = fmaxf(m0, xv[k].x * w);
                    m1 = fmaxf(m1, xv[k].y * w);
                }
            }
        }
        if (dg == 0) { m0 = 0.0f; m1 = 0.0f; }
        ((float2*)agg_s[r])[lane] = make_float2(m0, m1);
        float2 xr = *(const float2*)(xb + (size_t)node * (N_DIM * 4) + lane8);
        ((float2*)x_s[r])[lane] = xr;
        xsv[r] = xr;
    }

    const float4* WpR = Wp;
    const float4* WpO = Wp + 64 * 64;
    const float4* WpL = Wp + 2 * 64 * 64;

    // ---- GEMM1: h = agg @ W_rel^T + b_rel + x @ W_root^T ----
    float2 br = ((const float2*)b_rel)[lane];
    float2 acc[NPW];
    #pragma unroll
    for (int r = 0; r < NPW; r++) acc[r] = br;

    for (int i = 0; i < 32; i++) {        // k = 4i .. 4i+3
        float4 rA = WpR[(2*i)     * 64 + lane];
        float4 rB = WpR[(2*i + 1) * 64 + lane];
        float4 oA = WpO[(2*i)     * 64 + lane];
        float4 oB = WpO[(2*i + 1) * 64 + lane];
        float2 rA01 = make_float2(rA.x, rA.y), rA23 = make_float2(rA.z, rA.w);
        float2 rB01 = make_float2(rB.x, rB.y), rB23 = make_float2(rB.z, rB.w);
        float2 oA01 = make_float2(oA.x, oA.y), oA23 = make_float2(oA.z, oA.w);
        float2 oB01 = make_float2(oB.x, oB.y), oB23 = make_float2(oB.z, oB.w);
        #pragma unroll
        for (int r = 0; r < NPW; r++) {
            float4 a = *(const float4*)(agg_s[r] + 4*i);
            float4 xv = *(const float4*)(x_s[r] + 4*i);
            acc[r] = fma2(a.x, rA01, acc[r]);
            acc[r] = fma2(a.y, rA23, acc[r]);
            acc[r] = fma2(a.z, rB01, acc[r]);
            acc[r] = fma2(a.w, rB23, acc[r]);
            acc[r] = fma2(xv.x, oA01, acc[r]);
            acc[r] = fma2(xv.y, oA23, acc[r]);
            acc[r] = fma2(xv.z, oB01, acc[r]);
            acc[r] = fma2(xv.w, oB23, acc[r]);
        }
    }

    // ---- act + skip + LN #1 ----
    float2 gm = ((const float2*)gamma)[lane];
    float2 bt = ((const float2*)beta)[lane];
    float h0[NPW], h1[NPW], s[NPW], v[NPW];
    #pragma unroll
    for (int r = 0; r < NPW; r++) {
        h0[r] = gelu_exact(acc[r].x) + xsv[r].x;
        h1[r] = gelu_exact(acc[r].y) + xsv[r].y;
        s[r] = h0[r] + h1[r];
    }
    #pragma unroll
    for (int m = 32; m; m >>= 1)
        #pragma unroll
        for (int r = 0; r < NPW; r++) s[r] += __shfl_xor(s[r], m);
    #pragma unroll
    for (int r = 0; r < NPW; r++) {
        float mu = s[r] * (1.0f / 128.0f);
        h0[r] -= mu; h1[r] -= mu;
        v[r] = h0[r] * h0[r] + h1[r] * h1[r];
    }
    #pragma unroll
    for (int m = 32; m; m >>= 1)
        #pragma unroll
        for (int r = 0; r < NPW; r++) v[r] += __shfl_xor(v[r], m);
    float2 nrm[NPW];
    #pragma unroll
    for (int r = 0; r < NPW; r++) {
        float rstd = rsqrtf(v[r] * (1.0f / 128.0f) + LN_EPS);
        nrm[r].x = h0[r] * rstd * gm.x + bt.x;
        nrm[r].y = h1[r] * rstd * gm.y + bt.y;
        ((float2*)agg_s[r])[lane] = nrm[r];   // reuse agg_s for GEMM2 input
    }

    // ---- GEMM2: t = n @ lin_W^T + lin_b ----
    float2 lb = ((const float2*)lin_b)[lane];
    float2 acc2[NPW];
    #pragma unroll
    for (int r = 0; r < NPW; r++) acc2[r] = lb;

    for (int i = 0; i < 32; i++) {
        float4 lA = WpL[(2*i)     * 64 + lane];
        float4 lB = WpL[(2*i + 1) * 64 + lane];
        float2 lA01 = make_float2(lA.x, lA.y), lA23 = make_float2(lA.z, lA.w);
        float2 lB01 = make_float2(lB.x, lB.y), lB23 = make_float2(lB.z, lB.w);
        #pragma unroll
        for (int r = 0; r < NPW; r++) {
            float4 h = *(const float4*)(agg_s[r] + 4*i);
            acc2[r] = fma2(h.x, lA01, acc2[r]);
            acc2[r] = fma2(h.y, lA23, acc2[r]);
            acc2[r] = fma2(h.z, lB01, acc2[r]);
            acc2[r] = fma2(h.w, lB23, acc2[r]);
        }
    }

    // ---- act + skip + LN #2 + store ----
    float g0[NPW], g1[NPW];
    #pragma unroll
    for (int r = 0; r < NPW; r++) {
        g0[r] = gelu_exact(acc2[r].x) + nrm[r].x;
        g1[r] = gelu_exact(acc2[r].y) + nrm[r].y;
        s[r] = g0[r] + g1[r];
    }
    #pragma unroll
    for (int m = 32; m; m >>= 1)
        #pragma unroll
        for (int r = 0; r < NPW; r++) s[r] += __shfl_xor(s[r], m);
    #pragma unroll
    for (int r = 0; r < NPW; r++) {
        float mu = s[r] * (1.0f / 128.0f);
        g0[r] -= mu; g1[r] -= mu;
        v[r] = g0[r] * g0[r] + g1[r] * g1[r];
    }
    #pragma unroll
    for (int m = 32; m; m >>= 1)
        #pragma unroll
        for (int r = 0; r < NPW; r++) v[r] += __shfl_xor(v[r], m);
    #pragma unroll
    for (int r = 0; r < NPW; r++) {
        float rstd = rsqrtf(v[r] * (1.0f / 128.0f) + LN_EPS);
        float o0 = g0[r] * rstd * gm.x + bt.x;
        float o1 = g1[r] * rstd * gm.y + bt.y;
        ((float2*)(out + (size_t)(nb + r) * N_DIM))[lane] = make_float2(o0, o1);
    }
}

extern "C" void kernel_launch(void* const* d_in, const int* in_sizes, int n_in,
                              void* d_out, int out_size, void* d_ws, size_t ws_size,
                              hipStream_t stream) {
    const float* x      = (const float*)d_in[0];
    const int*   ei     = (const int*)  d_in[1];   // [2, E] int32
    const float* ew     = (const float*)d_in[2];
    const float* W_rel  = (const float*)d_in[3];
    const float* b_rel  = (const float*)d_in[4];
    const float* W_root = (const float*)d_in[5];
    const float* lin_W  = (const float*)d_in[6];
    const float* lin_b  = (const float*)d_in[7];
    const float* gamma  = (const float*)d_in[8];
    const float* beta   = (const float*)d_in[9];
    float* out = (float*)d_out;

    // ws layout: deg[N] | off[N] | cur[N] | csr int2[E] | Wp float4[3*64*64]
    int*    deg = (int*)d_ws;
    int*    off = deg + N_NODES;
    int*    cur = off + N_NODES;
    int2*   csr = (int2*)(cur + N_NODES);
    float4* Wp  = (float4*)(csr + N_EDGES);

    prep_kernel<<<(TASK_A + TASK_B + TASK_C + 255) / 256, 256, 0, stream>>>(
        ew, out + (size_t)N_NODES * N_DIM, W_rel, W_root, lin_W, Wp, (int4*)deg);
    hist_kernel<<<(N_EDGES / 4) / 256, 256, 0, stream>>>(ei, deg);
    scan_kernel<<<1, 1024, 0, stream>>>(deg, off, cur);
    fill_kernel<<<(N_EDGES + 255) / 256, 256, 0, stream>>>(ei, ew, cur, csr);
    fused_node_kernel<<<N_NODES / NPW, 64, 0, stream>>>(
        x, off, deg, csr, Wp, b_rel, lin_b, gamma, beta, out);
}

// Round 6
// 204.481 us; speedup vs baseline: 6.6898x; 1.1269x over previous
//
#include <hip/hip_runtime.h>
#include <math.h>

#define N_NODES 20000
#define N_DIM   128
#define N_EDGES 640000
#define LN_EPS  1e-5f
#define NPW 4              // nodes per wave; 1 wave per block

__device__ __forceinline__ float gelu_exact(float v) {
    return 0.5f * v * (1.0f + erff(v * 0.70710678118654752f));
}
__device__ __forceinline__ float2 fma2(float s, float2 w, float2 a) {
    a.x = fmaf(s, w.x, a.x);
    a.y = fmaf(s, w.y, a.y);
    return a;
}

// ---------------- prep: rank/hist (one atomic pass) + ew copy + weight repack ----
#define TASK_R 160000                 // E/4 rank int4 tasks (first: critical path)
#define TASK_A 160000                 // ew float4 copies
#define TASK_B 12288                  // 3*64*64 weight quads
__global__ __launch_bounds__(256) void prep_kernel(
    const int* __restrict__ ei, int* __restrict__ deg, int* __restrict__ rank,
    const float* __restrict__ ew, float* __restrict__ out_ew,
    const float* __restrict__ Wr, const float* __restrict__ Wo,
    const float* __restrict__ Wl, float4* __restrict__ Wp)
{
    int t = blockIdx.x * blockDim.x + threadIdx.x;
    if (t < TASK_R) {
        int4 d = ((const int4*)(ei + N_EDGES))[t];
        int4 r;
        r.x = atomicAdd(&deg[d.x], 1);
        r.y = atomicAdd(&deg[d.y], 1);
        r.z = atomicAdd(&deg[d.z], 1);
        r.w = atomicAdd(&deg[d.w], 1);
        ((int4*)rank)[t] = r;
    } else if (t < TASK_R + TASK_A) {
        int u = t - TASK_R;
        ((float4*)out_ew)[u] = ((const float4*)ew)[u];
    } else if (t < TASK_R + TASK_A + TASK_B) {
        int u = t - TASK_R - TASK_A;
        int m = u >> 12, r2 = u & 4095;
        int kp = r2 >> 6, p = r2 & 63;
        const float* W = (m == 0) ? Wr : ((m == 1) ? Wo : Wl);
        float4 v;
        v.x = W[(2*p)     * N_DIM + 2*kp];
        v.y = W[(2*p + 1) * N_DIM + 2*kp];
        v.z = W[(2*p)     * N_DIM + 2*kp + 1];
        v.w = W[(2*p + 1) * N_DIM + 2*kp + 1];
        Wp[u] = v;
    }
}

// ---------------- scan: off[0..N] (off[N] = E) ----------------
__global__ __launch_bounds__(1024) void scan_kernel(const int* __restrict__ deg,
                                                    int* __restrict__ off) {
    __shared__ int sm[1024];
    const int t = threadIdx.x;
    const int lo = t * 20;                 // 1000 threads carry data
    int4 d4[5];
    int s = 0;
    if (lo < N_NODES) {
        #pragma unroll
        for (int i = 0; i < 5; i++) {
            d4[i] = ((const int4*)(deg + lo))[i];
            s += d4[i].x + d4[i].y + d4[i].z + d4[i].w;
        }
    }
    sm[t] = s;
    __syncthreads();
    for (int d = 1; d < 1024; d <<= 1) {
        int v = (t >= d) ? sm[t - d] : 0;
        __syncthreads();
        sm[t] += v;
        __syncthreads();
    }
    int base = sm[t] - s;                  // exclusive prefix
    if (lo < N_NODES) {
        #pragma unroll
        for (int i = 0; i < 5; i++) {
            int4 o;
            o.x = base; base += d4[i].x;
            o.y = base; base += d4[i].y;
            o.z = base; base += d4[i].z;
            o.w = base; base += d4[i].w;
            ((int4*)(off + lo))[i] = o;
        }
    }
    if (t == 1023) off[N_NODES] = base;    // total = N_EDGES
}

// ---------------- fill: pure scatter, no atomics ----------------
__global__ __launch_bounds__(256) void fill_kernel(
    const int* __restrict__ ei, const float* __restrict__ ew,
    const int* __restrict__ rank, const int* __restrict__ off,
    int2* __restrict__ csr)
{
    int t = blockIdx.x * blockDim.x + threadIdx.x;   // E/4 threads
    int4 dst  = ((const int4*)(ei + N_EDGES))[t];
    int4 rk   = ((const int4*)rank)[t];
    int4 src  = ((const int4*)ei)[t];
    float4 w  = ((const float4*)ew)[t];
    csr[off[dst.x] + rk.x] = make_int2(src.x << 9, __float_as_int(w.x));
    csr[off[dst.y] + rk.y] = make_int2(src.y << 9, __float_as_int(w.y));
    csr[off[dst.z] + rk.z] = make_int2(src.z << 9, __float_as_int(w.z));
    csr[off[dst.w] + rk.w] = make_int2(src.w << 9, __float_as_int(w.w));
}

// ---------------- fused per-node pipeline ----------------
// 1 wave per block, 4 nodes per wave; gather interleaved across the 4 nodes
// (4 edges/node per iter -> up to 16 x-row loads in flight). No barriers.
__global__ __launch_bounds__(64) void fused_node_kernel(
    const float* __restrict__ x, const int* __restrict__ off,
    const int2* __restrict__ csr,
    const float4* __restrict__ Wp,       // [3][64][64]
    const float* __restrict__ b_rel, const float* __restrict__ lin_b,
    const float* __restrict__ gamma, const float* __restrict__ beta,
    float* __restrict__ out)
{
    __shared__ float agg_s[NPW][N_DIM];   // reused for normalized h before GEMM2
    __shared__ float x_s[NPW][N_DIM];

    const int lane = threadIdx.x & 63;
    const int nb = blockIdx.x * NPW;
    const int lane8 = lane << 3;          // byte offset of this lane's float2
    const char* xb = (const char*)x;

    int offs[NPW + 1];
    #pragma unroll
    for (int r = 0; r <= NPW; r++)
        offs[r] = __builtin_amdgcn_readfirstlane(off[nb + r]);

    // self rows early (overlap with gather)
    float2 xsv[NPW];
    #pragma unroll
    for (int r = 0; r < NPW; r++) {
        xsv[r] = *(const float2*)(xb + (size_t)(nb + r) * (N_DIM * 4) + lane8);
        ((float2*)x_s[r])[lane] = xsv[r];
    }

    int dg[NPW];
    int maxdg = 0;
    #pragma unroll
    for (int r = 0; r < NPW; r++) {
        dg[r] = offs[r + 1] - offs[r];
        maxdg = max(maxdg, dg[r]);
    }

    float m0[NPW], m1[NPW];
    #pragma unroll
    for (int r = 0; r < NPW; r++) { m0[r] = -INFINITY; m1[r] = -INFINITY; }

    for (int j = 0; j < maxdg; j += 4) {
        int2 ev[NPW][4];
        #pragma unroll
        for (int r = 0; r < NPW; r++) {
            if (j < dg[r]) {
                int b = offs[r] + j, hi = offs[r + 1] - 1;
                #pragma unroll
                for (int k = 0; k < 4; k++)
                    ev[r][k] = csr[min(b + k, hi)];   // clamp: dup fmax is a no-op
            }
        }
        float2 xv[NPW][4];
        #pragma unroll
        for (int r = 0; r < NPW; r++) {
            if (j < dg[r]) {
                #pragma unroll
                for (int k = 0; k < 4; k++)
                    xv[r][k] = *(const float2*)(xb + (size_t)(unsigned)ev[r][k].x + lane8);
            }
        }
        #pragma unroll
        for (int r = 0; r < NPW; r++) {
            if (j < dg[r]) {
                #pragma unroll
                for (int k = 0; k < 4; k++) {
                    float w = __int_as_float(ev[r][k].y);
                    m0[r] = fmaxf(m0[r], xv[r][k].x * w);
                    m1[r] = fmaxf(m1[r], xv[r][k].y * w);
                }
            }
        }
    }
    #pragma unroll
    for (int r = 0; r < NPW; r++) {
        if (dg[r] == 0) { m0[r] = 0.0f; m1[r] = 0.0f; }
        ((float2*)agg_s[r])[lane] = make_float2(m0[r], m1[r]);
    }

    const float4* WpR = Wp;
    const float4* WpO = Wp + 64 * 64;
    const float4* WpL = Wp + 2 * 64 * 64;

    // ---- GEMM1: h = agg @ W_rel^T + b_rel + x @ W_root^T ----
    float2 br = ((const float2*)b_rel)[lane];
    float2 acc[NPW];
    #pragma unroll
    for (int r = 0; r < NPW; r++) acc[r] = br;

    for (int i = 0; i < 32; i++) {        // k = 4i .. 4i+3
        float4 rA = WpR[(2*i)     * 64 + lane];
        float4 rB = WpR[(2*i + 1) * 64 + lane];
        float4 oA = WpO[(2*i)     * 64 + lane];
        float4 oB = WpO[(2*i + 1) * 64 + lane];
        float2 rA01 = make_float2(rA.x, rA.y), rA23 = make_float2(rA.z, rA.w);
        float2 rB01 = make_float2(rB.x, rB.y), rB23 = make_float2(rB.z, rB.w);
        float2 oA01 = make_float2(oA.x, oA.y), oA23 = make_float2(oA.z, oA.w);
        float2 oB01 = make_float2(oB.x, oB.y), oB23 = make_float2(oB.z, oB.w);
        #pragma unroll
        for (int r = 0; r < NPW; r++) {
            float4 a  = *(const float4*)(agg_s[r] + 4*i);
            float4 xv = *(const float4*)(x_s[r] + 4*i);
            acc[r] = fma2(a.x, rA01, acc[r]);
            acc[r] = fma2(a.y, rA23, acc[r]);
            acc[r] = fma2(a.z, rB01, acc[r]);
            acc[r] = fma2(a.w, rB23, acc[r]);
            acc[r] = fma2(xv.x, oA01, acc[r]);
            acc[r] = fma2(xv.y, oA23, acc[r]);
            acc[r] = fma2(xv.z, oB01, acc[r]);
            acc[r] = fma2(xv.w, oB23, acc[r]);
        }
    }

    // ---- act + skip + LN #1 ----
    float2 gm = ((const float2*)gamma)[lane];
    float2 bt = ((const float2*)beta)[lane];
    float h0[NPW], h1[NPW], s[NPW], v[NPW];
    #pragma unroll
    for (int r = 0; r < NPW; r++) {
        h0[r] = gelu_exact(acc[r].x) + xsv[r].x;
        h1[r] = gelu_exact(acc[r].y) + xsv[r].y;
        s[r] = h0[r] + h1[r];
    }
    #pragma unroll
    for (int m = 32; m; m >>= 1)
        #pragma unroll
        for (int r = 0; r < NPW; r++) s[r] += __shfl_xor(s[r], m);
    #pragma unroll
    for (int r = 0; r < NPW; r++) {
        float mu = s[r] * (1.0f / 128.0f);
        h0[r] -= mu; h1[r] -= mu;
        v[r] = h0[r] * h0[r] + h1[r] * h1[r];
    }
    #pragma unroll
    for (int m = 32; m; m >>= 1)
        #pragma unroll
        for (int r = 0; r < NPW; r++) v[r] += __shfl_xor(v[r], m);
    float2 nrm[NPW];
    #pragma unroll
    for (int r = 0; r < NPW; r++) {
        float rstd = rsqrtf(v[r] * (1.0f / 128.0f) + LN_EPS);
        nrm[r].x = h0[r] * rstd * gm.x + bt.x;
        nrm[r].y = h1[r] * rstd * gm.y + bt.y;
        ((float2*)agg_s[r])[lane] = nrm[r];   // reuse agg_s for GEMM2 input
    }

    // ---- GEMM2: t = n @ lin_W^T + lin_b ----
    float2 lb = ((const float2*)lin_b)[lane];
    float2 acc2[NPW];
    #pragma unroll
    for (int r = 0; r < NPW; r++) acc2[r] = lb;

    for (int i = 0; i < 32; i++) {
        float4 lA = WpL[(2*i)     * 64 + lane];
        float4 lB = WpL[(2*i + 1) * 64 + lane];
        float2 lA01 = make_float2(lA.x, lA.y), lA23 = make_float2(lA.z, lA.w);
        float2 lB01 = make_float2(lB.x, lB.y), lB23 = make_float2(lB.z, lB.w);
        #pragma unroll
        for (int r = 0; r < NPW; r++) {
            float4 h = *(const float4*)(agg_s[r] + 4*i);
            acc2[r] = fma2(h.x, lA01, acc2[r]);
            acc2[r] = fma2(h.y, lA23, acc2[r]);
            acc2[r] = fma2(h.z, lB01, acc2[r]);
            acc2[r] = fma2(h.w, lB23, acc2[r]);
        }
    }

    // ---- act + skip + LN #2 + store ----
    float g0[NPW], g1[NPW];
    #pragma unroll
    for (int r = 0; r < NPW; r++) {
        g0[r] = gelu_exact(acc2[r].x) + nrm[r].x;
        g1[r] = gelu_exact(acc2[r].y) + nrm[r].y;
        s[r] = g0[r] + g1[r];
    }
    #pragma unroll
    for (int m = 32; m; m >>= 1)
        #pragma unroll
        for (int r = 0; r < NPW; r++) s[r] += __shfl_xor(s[r], m);
    #pragma unroll
    for (int r = 0; r < NPW; r++) {
        float mu = s[r] * (1.0f / 128.0f);
        g0[r] -= mu; g1[r] -= mu;
        v[r] = g0[r] * g0[r] + g1[r] * g1[r];
    }
    #pragma unroll
    for (int m = 32; m; m >>= 1)
        #pragma unroll
        for (int r = 0; r < NPW; r++) v[r] += __shfl_xor(v[r], m);
    #pragma unroll
    for (int r = 0; r < NPW; r++) {
        float rstd = rsqrtf(v[r] * (1.0f / 128.0f) + LN_EPS);
        float o0 = g0[r] * rstd * gm.x + bt.x;
        float o1 = g1[r] * rstd * gm.y + bt.y;
        ((float2*)(out + (size_t)(nb + r) * N_DIM))[lane] = make_float2(o0, o1);
    }
}

extern "C" void kernel_launch(void* const* d_in, const int* in_sizes, int n_in,
                              void* d_out, int out_size, void* d_ws, size_t ws_size,
                              hipStream_t stream) {
    const float* x      = (const float*)d_in[0];
    const int*   ei     = (const int*)  d_in[1];   // [2, E] int32
    const float* ew     = (const float*)d_in[2];
    const float* W_rel  = (const float*)d_in[3];
    const float* b_rel  = (const float*)d_in[4];
    const float* W_root = (const float*)d_in[5];
    const float* lin_W  = (const float*)d_in[6];
    const float* lin_b  = (const float*)d_in[7];
    const float* gamma  = (const float*)d_in[8];
    const float* beta   = (const float*)d_in[9];
    float* out = (float*)d_out;

    // ws layout: deg[20000] | off[20004 incl pad] | rank[E] | csr int2[E] | Wp
    int*    deg  = (int*)d_ws;
    int*    off  = deg + N_NODES;
    int*    rank = off + (N_NODES + 4);            // 16B-aligned
    int2*   csr  = (int2*)(rank + N_EDGES);
    float4* Wp   = (float4*)(csr + N_EDGES);

    hipMemsetAsync(deg, 0, N_NODES * sizeof(int), stream);
    prep_kernel<<<(TASK_R + TASK_A + TASK_B) / 256, 256, 0, stream>>>(
        ei, deg, rank, ew, out + (size_t)N_NODES * N_DIM, W_rel, W_root, lin_W, Wp);
    scan_kernel<<<1, 1024, 0, stream>>>(deg, off);
    fill_kernel<<<(N_EDGES / 4) / 256, 256, 0, stream>>>(ei, ew, rank, off, csr);
    fused_node_kernel<<<N_NODES / NPW, 64, 0, stream>>>(
        x, off, csr, Wp, b_rel, lin_b, gamma, beta, out);
}